// Round 1
// baseline (352.176 us; speedup 1.0000x reference)
//
#include <hip/hip_runtime.h>
#include <cstdint>

using u16 = unsigned short;
using u32 = unsigned int;
typedef __attribute__((ext_vector_type(8))) short bf16x8;
typedef __attribute__((ext_vector_type(4))) float f32x4;
typedef __attribute__((ext_vector_type(4))) u16 u16x4;
typedef __attribute__((ext_vector_type(4))) u32 u32x4;

#define DEV static __device__ __forceinline__

DEV u16 bf16_rne(float x) {
  u32 u = __float_as_uint(x);
  u32 r = (u + 0x7FFFu + ((u >> 16) & 1u)) >> 16;
  return (u16)r;
}
DEV float bf16f(u16 h) { return __uint_as_float(((u32)h) << 16); }

DEV float fast_tanh(float x) {
  float e = __expf(2.0f * x);
  return 1.0f - 2.0f / (e + 1.0f);
}
DEV float sigmoidf_(float x) { return 1.0f / (1.0f + __expf(-x)); }

// ---------------------------------------------------------------------------
// prep: W_seq [D][P] f32  ->  Wt_hi/Wt_lo [P][D] bf16 (transposed, split)
// ---------------------------------------------------------------------------
__global__ void prep_wt(const float* __restrict__ W, u16* __restrict__ Wth,
                        u16* __restrict__ Wtl, int P, int D) {
  const int k = blockIdx.x;    // 0..D-1
  const int pp = threadIdx.x;  // 0..P-1
  float x = W[(long)k * P + pp];
  u16 h = bf16_rne(x);
  u16 l = bf16_rne(x - bf16f(h));
  Wth[(long)pp * D + k] = h;
  Wtl[(long)pp * D + k] = l;
}

// ---------------------------------------------------------------------------
// GEMM: seq_proj[M][256] = sequence[M][256] @ W_seq[256][256]
// split-bf16 MFMA (Ah*Bh + Al*Bh + Ah*Bl), BM=128, BN=256(full), BK=32
// 256 threads = 4 waves (2x2), per-wave 64x128 output (4x8 16x16 frags)
// ---------------------------------------------------------------------------
__global__ __launch_bounds__(256, 2) void gemm_seqproj(
    const float* __restrict__ A, const u16* __restrict__ Bhg,
    const u16* __restrict__ Blg, float* __restrict__ C) {
  __shared__ u16 sAh[128 * 32];
  __shared__ u16 sAl[128 * 32];
  __shared__ u16 sBh[256 * 32];
  __shared__ u16 sBl[256 * 32];

  const int t = threadIdx.x;
  const int lane = t & 63;
  const int w = t >> 6;
  const int wr = w >> 1, wc = w & 1;
  const int l15 = lane & 15, lg = lane >> 4;
  const long rowbase = (long)blockIdx.x * 128;

  // staging assignments
  const int arow = t >> 3;  // 0..31 (+32*i)
  const int akc = t & 7;    // which float4 of the 32-wide k strip
  const int bp = t >> 2;    // 0..63 (+64*i)
  const int bc = t & 3;     // which 8-elem chunk

  f32x4 acc[4][8];
#pragma unroll
  for (int i = 0; i < 4; ++i)
#pragma unroll
    for (int j = 0; j < 8; ++j) acc[i][j] = (f32x4)0.f;

  float4 ra[4];
  u32x4 rbh[4], rbl[4];

  auto loadTile = [&](int kt) {
    const int k0 = kt * 32;
#pragma unroll
    for (int i = 0; i < 4; ++i) {
      const int r = arow + i * 32;
      ra[i] = *(const float4*)(A + (rowbase + r) * 256 + k0 + akc * 4);
      const int p2 = bp + i * 64;
      rbh[i] = *(const u32x4*)(Bhg + (long)p2 * 256 + k0 + bc * 8);
      rbl[i] = *(const u32x4*)(Blg + (long)p2 * 256 + k0 + bc * 8);
    }
  };
  auto writeTile = [&]() {
#pragma unroll
    for (int i = 0; i < 4; ++i) {
      const int r = arow + i * 32;
      const int aidx = r * 32 + (((akc >> 1) ^ (r & 3)) << 3) + ((akc & 1) << 2);
      float xs0 = ra[i].x, xs1 = ra[i].y, xs2 = ra[i].z, xs3 = ra[i].w;
      u16x4 hi, lo;
      u16 h0 = bf16_rne(xs0); hi[0] = h0; lo[0] = bf16_rne(xs0 - bf16f(h0));
      u16 h1 = bf16_rne(xs1); hi[1] = h1; lo[1] = bf16_rne(xs1 - bf16f(h1));
      u16 h2 = bf16_rne(xs2); hi[2] = h2; lo[2] = bf16_rne(xs2 - bf16f(h2));
      u16 h3 = bf16_rne(xs3); hi[3] = h3; lo[3] = bf16_rne(xs3 - bf16f(h3));
      *(u16x4*)&sAh[aidx] = hi;
      *(u16x4*)&sAl[aidx] = lo;
      const int p2 = bp + i * 64;
      const int bidx = p2 * 32 + ((bc ^ (p2 & 3)) << 3);
      *(u32x4*)&sBh[bidx] = rbh[i];
      *(u32x4*)&sBl[bidx] = rbl[i];
    }
  };

  loadTile(0);
#pragma unroll 1
  for (int kt = 0; kt < 8; ++kt) {
    __syncthreads();  // previous compute done reading LDS
    writeTile();
    __syncthreads();
    if (kt < 7) loadTile(kt + 1);  // overlap global latency with compute
    // compute on LDS tile kt
    bf16x8 ah[4], al[4];
#pragma unroll
    for (int fm = 0; fm < 4; ++fm) {
      const int r = wr * 64 + fm * 16 + l15;
      const int idx = r * 32 + ((lg ^ (r & 3)) << 3);
      ah[fm] = *(bf16x8*)&sAh[idx];
      al[fm] = *(bf16x8*)&sAl[idx];
    }
#pragma unroll
    for (int fn = 0; fn < 8; ++fn) {
      const int pcol = wc * 128 + fn * 16 + l15;
      const int idx = pcol * 32 + ((lg ^ (pcol & 3)) << 3);
      bf16x8 bh = *(bf16x8*)&sBh[idx];
      bf16x8 bl = *(bf16x8*)&sBl[idx];
#pragma unroll
      for (int fm = 0; fm < 4; ++fm) {
        acc[fm][fn] = __builtin_amdgcn_mfma_f32_16x16x32_bf16(ah[fm], bh, acc[fm][fn], 0, 0, 0);
        acc[fm][fn] = __builtin_amdgcn_mfma_f32_16x16x32_bf16(al[fm], bh, acc[fm][fn], 0, 0, 0);
        acc[fm][fn] = __builtin_amdgcn_mfma_f32_16x16x32_bf16(ah[fm], bl, acc[fm][fn], 0, 0, 0);
      }
    }
  }

  // epilogue: C/D layout col=lane&15, row=(lane>>4)*4+reg
#pragma unroll
  for (int fm = 0; fm < 4; ++fm)
#pragma unroll
    for (int fn = 0; fn < 8; ++fn)
#pragma unroll
      for (int r = 0; r < 4; ++r) {
        const long grow = rowbase + wr * 64 + fm * 16 + lg * 4 + r;
        const int gcol = wc * 128 + fn * 16 + l15;
        C[grow * 256 + gcol] = acc[fm][fn][r];
      }
}

// ---------------------------------------------------------------------------
// hw[b][p] = sum_k h[b][k] * W_h[k][p]
// ---------------------------------------------------------------------------
__global__ __launch_bounds__(256) void hw_kernel(const float* __restrict__ h,
                                                 const float* __restrict__ Wh,
                                                 float* __restrict__ hw) {
  const int b = blockIdx.x, pp = threadIdx.x;
  __shared__ float sh[256];
  sh[pp] = h[b * 256 + pp];
  __syncthreads();
  float acc = 0.f;
#pragma unroll 4
  for (int k = 0; k < 256; ++k) acc = fmaf(sh[k], Wh[(long)k * 256 + pp], acc);
  hw[b * 256 + pp] = acc;
}

// ---------------------------------------------------------------------------
// scores[b][n] = sum_p v[p]*tanh(seq_proj[b][n][p] + hw[b][p]) + mask_bias
// ---------------------------------------------------------------------------
__global__ __launch_bounds__(256) void scores_kernel(
    const float* __restrict__ SP, const float* __restrict__ hw,
    const float* __restrict__ v, const float* __restrict__ mask,
    float* __restrict__ scores, int N) {
  const int b = blockIdx.y;
  const int n = blockIdx.x * 256 + threadIdx.x;
  __shared__ float shw[256], sv[256];
  shw[threadIdx.x] = hw[b * 256 + threadIdx.x];
  sv[threadIdx.x] = v[threadIdx.x];
  __syncthreads();
  const f32x4* row = (const f32x4*)(SP + ((long)b * N + n) * 256);
  const f32x4* h4 = (const f32x4*)shw;
  const f32x4* v4 = (const f32x4*)sv;
  float acc = 0.f;
#pragma unroll 8
  for (int j = 0; j < 64; ++j) {
    f32x4 s = row[j], hh = h4[j], vv = v4[j];
    acc = fmaf(vv[0], fast_tanh(s[0] + hh[0]), acc);
    acc = fmaf(vv[1], fast_tanh(s[1] + hh[1]), acc);
    acc = fmaf(vv[2], fast_tanh(s[2] + hh[2]), acc);
    acc = fmaf(vv[3], fast_tanh(s[3] + hh[3]), acc);
  }
  float mb = (mask[(long)b * N + n] > 0.f) ? 0.f : -1e9f;
  scores[(long)b * N + n] = acc + mb;
}

// ---------------------------------------------------------------------------
// softmax over n per b; writes w buffer and the [B][T][N] output slice
// ---------------------------------------------------------------------------
__global__ __launch_bounds__(256) void softmax_kernel(
    const float* __restrict__ scores, float* __restrict__ wout,
    float* __restrict__ outw, int N, int T, int step) {
  const int b = blockIdx.x, t = threadIdx.x;
  const int NC = N >> 8;  // assumes N % 256 == 0, NC <= 8
  __shared__ float sred[4];
  float loc[8];
  float m = -3.4e38f;
  for (int i = 0; i < NC; ++i) {
    loc[i] = scores[(long)b * N + i * 256 + t];
    m = fmaxf(m, loc[i]);
  }
#pragma unroll
  for (int o = 32; o; o >>= 1) m = fmaxf(m, __shfl_xor(m, o, 64));
  if ((t & 63) == 0) sred[t >> 6] = m;
  __syncthreads();
  m = fmaxf(fmaxf(sred[0], sred[1]), fmaxf(sred[2], sred[3]));
  __syncthreads();
  float s = 0.f;
  for (int i = 0; i < NC; ++i) {
    float e = __expf(loc[i] - m);
    loc[i] = e;
    s += e;
  }
#pragma unroll
  for (int o = 32; o; o >>= 1) s += __shfl_xor(s, o, 64);
  if ((t & 63) == 0) sred[t >> 6] = s;
  __syncthreads();
  s = (sred[0] + sred[1]) + (sred[2] + sred[3]);
  const float inv = 1.f / s;
  for (int i = 0; i < NC; ++i) {
    float wv = loc[i] * inv;
    wout[(long)b * N + i * 256 + t] = wv;
    outw[((long)b * T + step) * N + i * 256 + t] = wv;
  }
}

// ---------------------------------------------------------------------------
// vec partials: part[c][b][d] = sum_{n in chunk c} w[b][n]*sequence[b][n][d]
// ---------------------------------------------------------------------------
__global__ __launch_bounds__(256) void vec_partial(
    const float* __restrict__ seq, const float* __restrict__ wbuf,
    float* __restrict__ part, int N, int B) {
  const int b = blockIdx.y, c = blockIdx.x, d = threadIdx.x;
  __shared__ float sw[256];
  sw[d] = wbuf[(long)b * N + c * 256 + d];
  __syncthreads();
  const float* base = seq + ((long)b * N + c * 256) * 256 + d;
  float a0 = 0, a1 = 0, a2 = 0, a3 = 0;
#pragma unroll 4
  for (int i = 0; i < 256; i += 4) {
    a0 = fmaf(sw[i], base[(long)i * 256], a0);
    a1 = fmaf(sw[i + 1], base[(long)(i + 1) * 256], a1);
    a2 = fmaf(sw[i + 2], base[(long)(i + 2) * 256], a2);
    a3 = fmaf(sw[i + 3], base[(long)(i + 3) * 256], a3);
  }
  part[((long)c * B + b) * 256 + d] = (a0 + a1) + (a2 + a3);
}

// ---------------------------------------------------------------------------
// GRU cell: reduce partials -> vec; gates; h_new
// ---------------------------------------------------------------------------
__global__ __launch_bounds__(256) void gru_kernel(
    const float* __restrict__ part, const float* __restrict__ hprev,
    const float* __restrict__ Wih, const float* __restrict__ Whh,
    const float* __restrict__ bih, const float* __restrict__ bhh,
    float* __restrict__ hnew, int B, int NC) {
  const int b = blockIdx.x, j = threadIdx.x;
  __shared__ float sv[256], sh[256];
  float a = 0.f;
  for (int c = 0; c < NC; ++c) a += part[((long)c * B + b) * 256 + j];
  sv[j] = a;
  sh[j] = hprev[b * 256 + j];
  __syncthreads();
  float xr = bih[j], xz = bih[256 + j], xn = bih[512 + j];
  float hr = bhh[j], hz = bhh[256 + j], hn = bhh[512 + j];
  const float* wr_ = Wih + (long)j * 256;
  const float* wz_ = Wih + (long)(256 + j) * 256;
  const float* wn_ = Wih + (long)(512 + j) * 256;
  const float* ur_ = Whh + (long)j * 256;
  const float* uz_ = Whh + (long)(256 + j) * 256;
  const float* un_ = Whh + (long)(512 + j) * 256;
  for (int d = 0; d < 256; ++d) {
    float vd = sv[d], hd = sh[d];
    xr = fmaf(vd, wr_[d], xr);
    xz = fmaf(vd, wz_[d], xz);
    xn = fmaf(vd, wn_[d], xn);
    hr = fmaf(hd, ur_[d], hr);
    hz = fmaf(hd, uz_[d], hz);
    hn = fmaf(hd, un_[d], hn);
  }
  float r = sigmoidf_(xr + hr);
  float z = sigmoidf_(xz + hz);
  float nn = fast_tanh(xn + r * hn);
  hnew[b * 256 + j] = (1.f - z) * nn + z * sh[j];
}

// ---------------------------------------------------------------------------
extern "C" void kernel_launch(void* const* d_in, const int* in_sizes, int n_in,
                              void* d_out, int out_size, void* d_ws,
                              size_t ws_size, hipStream_t stream) {
  (void)n_in;
  (void)ws_size;
  const float* seq = (const float*)d_in[0];
  const float* hidden = (const float*)d_in[1];
  const float* mask = (const float*)d_in[2];
  // d_in[3] = num_steps (device scalar) — T derived from out_size instead
  const float* Wseq = (const float*)d_in[4];
  const float* Wh = (const float*)d_in[5];
  const float* vatt = (const float*)d_in[6];
  const float* Wih = (const float*)d_in[7];
  const float* Whh = (const float*)d_in[8];
  const float* bih = (const float*)d_in[9];
  const float* bhh = (const float*)d_in[10];
  float* out = (float*)d_out;

  const int P = in_sizes[6];
  const int D = in_sizes[4] / P;
  const int H = in_sizes[5] / P;
  const int B = in_sizes[1] / H;
  const int N = in_sizes[2] / B;
  const int T = out_size / (B * N);
  const long M = (long)B * N;
  const int NC = N / 256;

  char* p = (char*)d_ws;
  auto alloc = [&](size_t bytes) {
    char* r = p;
    p += (bytes + 255) & ~(size_t)255;
    return r;
  };
  float* seqproj = (float*)alloc((size_t)M * P * 4);
  u16* Wth = (u16*)alloc((size_t)P * D * 2);
  u16* Wtl = (u16*)alloc((size_t)P * D * 2);
  float* scores = (float*)alloc((size_t)B * N * 4);
  float* wbuf = (float*)alloc((size_t)B * N * 4);
  float* hwbuf = (float*)alloc((size_t)B * P * 4);
  float* hA = (float*)alloc((size_t)B * H * 4);
  float* hB = (float*)alloc((size_t)B * H * 4);
  float* part = (float*)alloc((size_t)NC * B * 256 * 4);
  float* hbuf[2] = {hA, hB};

  prep_wt<<<dim3(D), dim3(P), 0, stream>>>(Wseq, Wth, Wtl, P, D);
  gemm_seqproj<<<dim3((int)(M / 128)), dim3(256), 0, stream>>>(seq, Wth, Wtl,
                                                               seqproj);

  const float* hcur = hidden;
  for (int t = 0; t < T; ++t) {
    hw_kernel<<<dim3(B), dim3(256), 0, stream>>>(hcur, Wh, hwbuf);
    scores_kernel<<<dim3(NC, B), dim3(256), 0, stream>>>(seqproj, hwbuf, vatt,
                                                         mask, scores, N);
    softmax_kernel<<<dim3(B), dim3(256), 0, stream>>>(scores, wbuf, out, N, T, t);
    vec_partial<<<dim3(NC, B), dim3(256), 0, stream>>>(seq, wbuf, part, N, B);
    gru_kernel<<<dim3(B), dim3(256), 0, stream>>>(part, hcur, Wih, Whh, bih,
                                                  bhh, hbuf[t & 1], B, NC);
    hcur = hbuf[t & 1];
  }
}

// Round 2
// 272.610 us; speedup vs baseline: 1.2919x; 1.2919x over previous
//
#include <hip/hip_runtime.h>
#include <cstdint>

using u16 = unsigned short;
using u32 = unsigned int;
typedef __attribute__((ext_vector_type(8))) short bf16x8;
typedef __attribute__((ext_vector_type(4))) float f32x4;
typedef __attribute__((ext_vector_type(4))) u16 u16x4;
typedef __attribute__((ext_vector_type(4))) u32 u32x4;

#define DEV static __device__ __forceinline__

DEV u16 bf16_rne(float x) {
  u32 u = __float_as_uint(x);
  u32 r = (u + 0x7FFFu + ((u >> 16) & 1u)) >> 16;
  return (u16)r;
}
DEV float bf16f(u16 h) { return __uint_as_float(((u32)h) << 16); }

DEV float fast_tanh(float x) {
  float e = __expf(2.0f * x);
  return 1.0f - 2.0f / (e + 1.0f);
}
DEV float sigmoidf_(float x) { return 1.0f / (1.0f + __expf(-x)); }

// ---------------------------------------------------------------------------
// prep: W_seq [D][P] f32 -> Wtb [P][D] bf16 (transposed, single bf16)
// ---------------------------------------------------------------------------
__global__ void prep_wt(const float* __restrict__ W, u16* __restrict__ Wtb,
                        int P, int D) {
  const int k = blockIdx.x;    // 0..D-1
  const int pp = threadIdx.x;  // 0..P-1
  Wtb[(long)pp * D + k] = bf16_rne(W[(long)k * P + pp]);
}

// prep: transpose GRU weights: WihT[d][g]=Wih[g][d], WhhT[d][g]=Whh[g][d]
// (assumes D == H)
__global__ void prep_grut(const float* __restrict__ Wih,
                          const float* __restrict__ Whh,
                          float* __restrict__ WT, float* __restrict__ UT,
                          int G, int Dd) {
  const int g = blockIdx.x;    // 0..G-1 (G=3H)
  const int d = threadIdx.x;   // 0..D-1
  WT[(long)d * G + g] = Wih[(long)g * Dd + d];
  UT[(long)d * G + g] = Whh[(long)g * Dd + d];
}

// ---------------------------------------------------------------------------
// hw[b][p] = sum_k h[b][k] * W_h[k][p]   (coalesced over pp)
// ---------------------------------------------------------------------------
__global__ __launch_bounds__(256) void hw_kernel(const float* __restrict__ h,
                                                 const float* __restrict__ Wh,
                                                 float* __restrict__ hw) {
  const int b = blockIdx.x, pp = threadIdx.x;
  __shared__ float sh[256];
  sh[pp] = h[b * 256 + pp];
  __syncthreads();
  float acc = 0.f;
#pragma unroll 4
  for (int k = 0; k < 256; ++k) acc = fmaf(sh[k], Wh[(long)k * 256 + pp], acc);
  hw[b * 256 + pp] = acc;
}

// ---------------------------------------------------------------------------
// Fused GEMM: SP(bf16)[M][256] = sequence[M][256] @ W_seq, also:
//  - seqb = bf16(sequence)
//  - scores(step0)[row] = sum_p v[p]*tanh(acc[p] + hw0[b][p])  (mask in softmax)
// 2-product split-A bf16 MFMA, BM=128, BN=256 (full P), BK=32, 4 waves 2x2.
// ---------------------------------------------------------------------------
__global__ __launch_bounds__(256, 2) void gemm_fused(
    const float* __restrict__ A, const u16* __restrict__ Bt,
    const float* __restrict__ hw0, const float* __restrict__ vatt,
    u16* __restrict__ SP, u16* __restrict__ seqb, float* __restrict__ scores,
    int N) {
  __shared__ u16 sAh[128 * 32];
  __shared__ u16 sAl[128 * 32];
  __shared__ u16 sB[256 * 32];
  __shared__ float sred[128][2];

  const int t = threadIdx.x;
  const int lane = t & 63;
  const int w = t >> 6;
  const int wr = w >> 1, wc = w & 1;
  const int l15 = lane & 15, lg = lane >> 4;
  const long rowbase = (long)blockIdx.x * 128;

  const int arow = t >> 3;  // 0..31 (+32*i)
  const int akc = t & 7;    // float4 index in 32-wide k strip
  const int bp = t >> 2;    // 0..63 (+64*i)
  const int bc = t & 3;     // 8-elem chunk

  f32x4 acc[4][8];
#pragma unroll
  for (int i = 0; i < 4; ++i)
#pragma unroll
    for (int j = 0; j < 8; ++j) acc[i][j] = (f32x4)0.f;

  float4 ra[4];
  u32x4 rb[4];

  auto loadTile = [&](int kt) {
    const int k0 = kt * 32;
#pragma unroll
    for (int i = 0; i < 4; ++i) {
      const int r = arow + i * 32;
      ra[i] = *(const float4*)(A + (rowbase + r) * 256 + k0 + akc * 4);
      const int p2 = bp + i * 64;
      rb[i] = *(const u32x4*)(Bt + (long)p2 * 256 + k0 + (bc ^ (p2 & 3)) * 8);
    }
  };
  auto writeTile = [&](int kt) {
    const int k0 = kt * 32;
#pragma unroll
    for (int i = 0; i < 4; ++i) {
      const int r = arow + i * 32;
      const int aidx = r * 32 + (((akc >> 1) ^ (r & 3)) << 3) + ((akc & 1) << 2);
      u16x4 hi, lo;
      float x0 = ra[i].x, x1 = ra[i].y, x2 = ra[i].z, x3 = ra[i].w;
      u16 h0 = bf16_rne(x0); hi[0] = h0; lo[0] = bf16_rne(x0 - bf16f(h0));
      u16 h1 = bf16_rne(x1); hi[1] = h1; lo[1] = bf16_rne(x1 - bf16f(h1));
      u16 h2 = bf16_rne(x2); hi[2] = h2; lo[2] = bf16_rne(x2 - bf16f(h2));
      u16 h3 = bf16_rne(x3); hi[3] = h3; lo[3] = bf16_rne(x3 - bf16f(h3));
      *(u16x4*)&sAh[aidx] = hi;
      *(u16x4*)&sAl[aidx] = lo;
      *(u16x4*)&seqb[(rowbase + r) * 256 + k0 + akc * 4] = hi;  // bf16 copy
      const int p2 = bp + i * 64;
      const int bidx = p2 * 32 + (bc << 3);  // swizzle applied on global src
      *(u32x4*)&sB[bidx] = rb[i];
    }
  };

  loadTile(0);
#pragma unroll 1
  for (int kt = 0; kt < 8; ++kt) {
    __syncthreads();
    writeTile(kt);
    __syncthreads();
    if (kt < 7) loadTile(kt + 1);
    bf16x8 ah[4], al[4];
#pragma unroll
    for (int fm = 0; fm < 4; ++fm) {
      const int r = wr * 64 + fm * 16 + l15;
      const int idx = r * 32 + ((lg ^ (r & 3)) << 3);
      ah[fm] = *(bf16x8*)&sAh[idx];
      al[fm] = *(bf16x8*)&sAl[idx];
    }
#pragma unroll
    for (int fn = 0; fn < 8; ++fn) {
      const int pcol = wc * 128 + fn * 16 + l15;
      const int idx = pcol * 32 + ((lg ^ (pcol & 3)) << 3);
      bf16x8 bh = *(bf16x8*)&sB[idx];
#pragma unroll
      for (int fm = 0; fm < 4; ++fm) {
        acc[fm][fn] = __builtin_amdgcn_mfma_f32_16x16x32_bf16(ah[fm], bh, acc[fm][fn], 0, 0, 0);
        acc[fm][fn] = __builtin_amdgcn_mfma_f32_16x16x32_bf16(al[fm], bh, acc[fm][fn], 0, 0, 0);
      }
    }
  }

  // --- store SP as bf16; C/D layout col=lane&15, row=(lane>>4)*4+reg ---
#pragma unroll
  for (int fm = 0; fm < 4; ++fm)
#pragma unroll
    for (int fn = 0; fn < 8; ++fn)
#pragma unroll
      for (int r = 0; r < 4; ++r) {
        const long grow = rowbase + wr * 64 + fm * 16 + lg * 4 + r;
        const int gcol = wc * 128 + fn * 16 + l15;
        SP[grow * 256 + gcol] = bf16_rne(acc[fm][fn][r]);
      }

  // --- fused step-0 scores: per-lane partial over its 8 cols ---
  const int bb = (int)(rowbase / N);
  float vf[8], hwf[8];
#pragma unroll
  for (int fn = 0; fn < 8; ++fn) {
    const int c = wc * 128 + fn * 16 + l15;
    vf[fn] = vatt[c];
    hwf[fn] = hw0[bb * 256 + c];
  }
  float part[4][4];
#pragma unroll
  for (int fm = 0; fm < 4; ++fm)
#pragma unroll
    for (int r = 0; r < 4; ++r) {
      float s = 0.f;
#pragma unroll
      for (int fn = 0; fn < 8; ++fn)
        s = fmaf(vf[fn], fast_tanh(acc[fm][fn][r] + hwf[fn]), s);
      part[fm][r] = s;
    }
#pragma unroll
  for (int off = 1; off < 16; off <<= 1)
#pragma unroll
    for (int fm = 0; fm < 4; ++fm)
#pragma unroll
      for (int r = 0; r < 4; ++r)
        part[fm][r] += __shfl_xor(part[fm][r], off, 16);
  if (l15 == 0) {
#pragma unroll
    for (int fm = 0; fm < 4; ++fm)
#pragma unroll
      for (int r = 0; r < 4; ++r)
        sred[wr * 64 + fm * 16 + lg * 4 + r][wc] = part[fm][r];
  }
  __syncthreads();
  if (t < 128) scores[rowbase + t] = sred[t][0] + sred[t][1];
}

// ---------------------------------------------------------------------------
// scores[b][n] = sum_p v[p]*tanh(SP_bf16[b][n][p] + hw[b][p])   (steps >= 1)
// ---------------------------------------------------------------------------
__global__ __launch_bounds__(256) void scores_kernel(
    const u16* __restrict__ SP, const float* __restrict__ hw,
    const float* __restrict__ v, float* __restrict__ scores, int N) {
  const int b = blockIdx.y;
  const int n = blockIdx.x * 256 + threadIdx.x;
  __shared__ float shw[256], sv[256];
  shw[threadIdx.x] = hw[b * 256 + threadIdx.x];
  sv[threadIdx.x] = v[threadIdx.x];
  __syncthreads();
  const bf16x8* row = (const bf16x8*)(SP + ((long)b * N + n) * 256);
  float acc = 0.f;
#pragma unroll 8
  for (int j = 0; j < 32; ++j) {
    bf16x8 q = row[j];
#pragma unroll
    for (int e = 0; e < 8; ++e) {
      float x = bf16f((u16)q[e]) + shw[j * 8 + e];
      acc = fmaf(sv[j * 8 + e], fast_tanh(x), acc);
    }
  }
  scores[(long)b * N + n] = acc;
}

// ---------------------------------------------------------------------------
// softmax over n per b (mask bias applied here); writes w buffer + out slice
// ---------------------------------------------------------------------------
__global__ __launch_bounds__(256) void softmax_kernel(
    const float* __restrict__ scores, const float* __restrict__ mask,
    float* __restrict__ wout, float* __restrict__ outw, int N, int T,
    int step) {
  const int b = blockIdx.x, t = threadIdx.x;
  const int NC = N >> 8;
  __shared__ float sred[4];
  float loc[8];
  float m = -3.4e38f;
  for (int i = 0; i < NC; ++i) {
    float s = scores[(long)b * N + i * 256 + t];
    s += (mask[(long)b * N + i * 256 + t] > 0.f) ? 0.f : -1e9f;
    loc[i] = s;
    m = fmaxf(m, s);
  }
#pragma unroll
  for (int o = 32; o; o >>= 1) m = fmaxf(m, __shfl_xor(m, o, 64));
  if ((t & 63) == 0) sred[t >> 6] = m;
  __syncthreads();
  m = fmaxf(fmaxf(sred[0], sred[1]), fmaxf(sred[2], sred[3]));
  __syncthreads();
  float s = 0.f;
  for (int i = 0; i < NC; ++i) {
    float e = __expf(loc[i] - m);
    loc[i] = e;
    s += e;
  }
#pragma unroll
  for (int o = 32; o; o >>= 1) s += __shfl_xor(s, o, 64);
  if ((t & 63) == 0) sred[t >> 6] = s;
  __syncthreads();
  s = (sred[0] + sred[1]) + (sred[2] + sred[3]);
  const float inv = 1.f / s;
  for (int i = 0; i < NC; ++i) {
    float wv = loc[i] * inv;
    wout[(long)b * N + i * 256 + t] = wv;
    outw[((long)b * T + step) * N + i * 256 + t] = wv;
  }
}

// ---------------------------------------------------------------------------
// vec partials from bf16 sequence copy; coalesced 8B/lane loads.
// thread = (d4 = t&63 -> 4 d's, isub = t>>6 -> 64-row group)
// part[(c*4+isub)][b][d] = sum_{rows} w*seqb
// ---------------------------------------------------------------------------
__global__ __launch_bounds__(256) void vec_partial(
    const u16* __restrict__ seqb, const float* __restrict__ wbuf,
    float* __restrict__ part, int N, int B) {
  const int b = blockIdx.y, c = blockIdx.x, t = threadIdx.x;
  const int d4 = t & 63, isub = t >> 6;
  __shared__ float sw[256];
  sw[t] = wbuf[(long)b * N + c * 256 + t];
  __syncthreads();
  const u16* base = seqb + ((long)b * N + c * 256 + isub * 64) * 256 + d4 * 4;
  float a0 = 0, a1 = 0, a2 = 0, a3 = 0;
#pragma unroll 4
  for (int ii = 0; ii < 64; ++ii) {
    u16x4 q = *(const u16x4*)(base + (long)ii * 256);
    float wv = sw[isub * 64 + ii];
    a0 = fmaf(wv, bf16f(q[0]), a0);
    a1 = fmaf(wv, bf16f(q[1]), a1);
    a2 = fmaf(wv, bf16f(q[2]), a2);
    a3 = fmaf(wv, bf16f(q[3]), a3);
  }
  float4 res = {a0, a1, a2, a3};
  *(float4*)&part[((long)(c * 4 + isub) * B + b) * 256 + d4 * 4] = res;
}

// ---------------------------------------------------------------------------
// GRU cell with transposed weights (coalesced): WT/UT are [D][3H]
// ---------------------------------------------------------------------------
__global__ __launch_bounds__(256) void gru_kernel(
    const float* __restrict__ part, const float* __restrict__ hprev,
    const float* __restrict__ WT, const float* __restrict__ UT,
    const float* __restrict__ bih, const float* __restrict__ bhh,
    float* __restrict__ hnew, int B, int NP) {
  const int b = blockIdx.x, j = threadIdx.x;
  __shared__ float sv[256], sh[256];
  float a = 0.f;
  for (int c = 0; c < NP; ++c) a += part[((long)c * B + b) * 256 + j];
  sv[j] = a;
  sh[j] = hprev[b * 256 + j];
  __syncthreads();
  float xr = bih[j], xz = bih[256 + j], xn = bih[512 + j];
  float hr = bhh[j], hz = bhh[256 + j], hn = bhh[512 + j];
#pragma unroll 4
  for (int d = 0; d < 256; ++d) {
    float vd = sv[d], hd = sh[d];
    const float* wrow = WT + (long)d * 768;
    const float* urow = UT + (long)d * 768;
    xr = fmaf(vd, wrow[j], xr);
    xz = fmaf(vd, wrow[256 + j], xz);
    xn = fmaf(vd, wrow[512 + j], xn);
    hr = fmaf(hd, urow[j], hr);
    hz = fmaf(hd, urow[256 + j], hz);
    hn = fmaf(hd, urow[512 + j], hn);
  }
  float r = sigmoidf_(xr + hr);
  float z = sigmoidf_(xz + hz);
  float nn = fast_tanh(xn + r * hn);
  hnew[b * 256 + j] = (1.f - z) * nn + z * sh[j];
}

// ---------------------------------------------------------------------------
extern "C" void kernel_launch(void* const* d_in, const int* in_sizes, int n_in,
                              void* d_out, int out_size, void* d_ws,
                              size_t ws_size, hipStream_t stream) {
  (void)n_in;
  (void)ws_size;
  const float* seq = (const float*)d_in[0];
  const float* hidden = (const float*)d_in[1];
  const float* mask = (const float*)d_in[2];
  const float* Wseq = (const float*)d_in[4];
  const float* Wh = (const float*)d_in[5];
  const float* vatt = (const float*)d_in[6];
  const float* Wih = (const float*)d_in[7];
  const float* Whh = (const float*)d_in[8];
  const float* bih = (const float*)d_in[9];
  const float* bhh = (const float*)d_in[10];
  float* out = (float*)d_out;

  const int P = in_sizes[6];
  const int D = in_sizes[4] / P;
  const int H = in_sizes[5] / P;
  const int B = in_sizes[1] / H;
  const int N = in_sizes[2] / B;
  const int T = out_size / (B * N);
  const long M = (long)B * N;
  const int NC = N / 256;

  char* p = (char*)d_ws;
  auto alloc = [&](size_t bytes) {
    char* r = p;
    p += (bytes + 255) & ~(size_t)255;
    return r;
  };
  u16* SP = (u16*)alloc((size_t)M * P * 2);
  u16* seqb = (u16*)alloc((size_t)M * D * 2);
  u16* Wtb = (u16*)alloc((size_t)P * D * 2);
  float* WihT = (float*)alloc((size_t)D * 3 * H * 4);
  float* WhhT = (float*)alloc((size_t)H * 3 * H * 4);
  float* scores = (float*)alloc((size_t)B * N * 4);
  float* wbuf = (float*)alloc((size_t)B * N * 4);
  float* hwbuf = (float*)alloc((size_t)B * P * 4);
  float* hA = (float*)alloc((size_t)B * H * 4);
  float* hB = (float*)alloc((size_t)B * H * 4);
  float* part = (float*)alloc((size_t)NC * 4 * B * 256 * 4);
  float* hbuf[2] = {hA, hB};

  prep_wt<<<dim3(D), dim3(P), 0, stream>>>(Wseq, Wtb, P, D);
  prep_grut<<<dim3(3 * H), dim3(D), 0, stream>>>(Wih, Whh, WihT, WhhT, 3 * H, D);
  hw_kernel<<<dim3(B), dim3(256), 0, stream>>>(hidden, Wh, hwbuf);
  gemm_fused<<<dim3((int)(M / 128)), dim3(256), 0, stream>>>(
      seq, Wtb, hwbuf, vatt, SP, seqb, scores, N);

  const float* hcur = hidden;
  for (int t = 0; t < T; ++t) {
    if (t > 0) {
      hw_kernel<<<dim3(B), dim3(256), 0, stream>>>(hcur, Wh, hwbuf);
      scores_kernel<<<dim3(NC, B), dim3(256), 0, stream>>>(SP, hwbuf, vatt,
                                                           scores, N);
    }
    softmax_kernel<<<dim3(B), dim3(256), 0, stream>>>(scores, mask, wbuf, out,
                                                      N, T, t);
    vec_partial<<<dim3(NC, B), dim3(256), 0, stream>>>(seqb, wbuf, part, N, B);
    gru_kernel<<<dim3(B), dim3(256), 0, stream>>>(part, hcur, WihT, WhhT, bih,
                                                  bhh, hbuf[t & 1], B, NC * 4);
    hcur = hbuf[t & 1];
  }
}

// Round 3
// 225.132 us; speedup vs baseline: 1.5643x; 1.2109x over previous
//
#include <hip/hip_runtime.h>
#include <cstdint>

using u16 = unsigned short;
using u32 = unsigned int;
typedef __attribute__((ext_vector_type(8))) short bf16x8;
typedef __attribute__((ext_vector_type(8))) u16 u16x8;
typedef __attribute__((ext_vector_type(4))) float f32x4;
typedef __attribute__((ext_vector_type(4))) u16 u16x4;
typedef __attribute__((ext_vector_type(4))) u32 u32x4;

#define DEV static __device__ __forceinline__

DEV u16 bf16_rne(float x) {
  u32 u = __float_as_uint(x);
  u32 r = (u + 0x7FFFu + ((u >> 16) & 1u)) >> 16;
  return (u16)r;
}
DEV float bf16f(u16 h) { return __uint_as_float(((u32)h) << 16); }

DEV float fast_tanh(float x) {
  float e = __expf(2.0f * x);
  return 1.0f - 2.0f / (e + 1.0f);
}
DEV float sigmoidf_(float x) { return 1.0f / (1.0f + __expf(-x)); }

// ---------------------------------------------------------------------------
// prep: W_seq [D][P] f32 -> Wtb [P][D] bf16 (transposed)
// ---------------------------------------------------------------------------
__global__ void prep_wt(const float* __restrict__ W, u16* __restrict__ Wtb,
                        int P, int D) {
  const int k = blockIdx.x;
  const int pp = threadIdx.x;
  Wtb[(long)pp * D + k] = bf16_rne(W[(long)k * P + pp]);
}

// prep: transpose GRU weights
__global__ void prep_grut(const float* __restrict__ Wih,
                          const float* __restrict__ Whh,
                          float* __restrict__ WT, float* __restrict__ UT,
                          int G, int Dd) {
  const int g = blockIdx.x;
  const int d = threadIdx.x;
  WT[(long)d * G + g] = Wih[(long)g * Dd + d];
  UT[(long)d * G + g] = Whh[(long)g * Dd + d];
}

// ---------------------------------------------------------------------------
// hw[b][p] = sum_k h[b][k] * W_h[k][p]
// ---------------------------------------------------------------------------
__global__ __launch_bounds__(256) void hw_kernel(const float* __restrict__ h,
                                                 const float* __restrict__ Wh,
                                                 float* __restrict__ hw) {
  const int b = blockIdx.x, pp = threadIdx.x;
  __shared__ float sh[256];
  sh[pp] = h[b * 256 + pp];
  __syncthreads();
  float acc = 0.f;
#pragma unroll 4
  for (int k = 0; k < 256; ++k) acc = fmaf(sh[k], Wh[(long)k * 256 + pp], acc);
  hw[b * 256 + pp] = acc;
}

// ---------------------------------------------------------------------------
// Fused GEMM: A direct-to-reg, B LDS double-buffered, single-product bf16.
// 4 waves; wave w owns rows w*32..w*32+31, ALL 256 cols.
// Emits: SP bf16, seqb bf16, step-0 e=exp(score) into wbuf, per-block esum.
// ---------------------------------------------------------------------------
__global__ __launch_bounds__(256, 2) void gemm_fused(
    const float* __restrict__ A, const u16* __restrict__ Bt,
    const float* __restrict__ hw0, const float* __restrict__ vatt,
    const float* __restrict__ mask, u16* __restrict__ SP,
    u16* __restrict__ seqb, float* __restrict__ wbuf,
    float* __restrict__ esum0, int N) {
  __shared__ u16 sB[2][4][256 * 8];  // [buf][k-plane 16B][col*8] = 32 KB
  __shared__ float sredE[4];

  const int t = threadIdx.x;
  const int lane = t & 63;
  const int w = t >> 6;
  const int l15 = lane & 15, lg = lane >> 4;
  const long rowbase = (long)blockIdx.x * 128;
  const long gr0 = rowbase + w * 32 + l15;
  const long gr1 = gr0 + 16;

  const u16* bsrc = Bt + (long)t * 256;  // col = t, [col][k]
  const float* as0 = A + gr0 * 256 + lg * 8;
  const float* as1 = A + gr1 * 256 + lg * 8;
  u16* sq0 = seqb + gr0 * 256 + lg * 8;
  u16* sq1 = seqb + gr1 * 256 + lg * 8;

  f32x4 acc[2][16];
#pragma unroll
  for (int i = 0; i < 2; ++i)
#pragma unroll
    for (int j = 0; j < 16; ++j) acc[i][j] = (f32x4)0.f;

  float4 a0[2][2], a1[2][2];
  u32x4 brg[2][4];

  // prologue: tile 0
#pragma unroll
  for (int c = 0; c < 4; ++c) brg[0][c] = *(const u32x4*)(bsrc + c * 8);
#pragma unroll
  for (int h = 0; h < 2; ++h) {
    a0[0][h] = *(const float4*)(as0 + h * 4);
    a1[0][h] = *(const float4*)(as1 + h * 4);
  }
#pragma unroll
  for (int c = 0; c < 4; ++c) *(u32x4*)&sB[0][c][t * 8] = brg[0][c];
  __syncthreads();

#pragma unroll
  for (int kt = 0; kt < 8; ++kt) {
    const int cur = kt & 1, nxt = cur ^ 1;
    if (kt < 7) {  // prefetch next tile into regs
      const int k0 = (kt + 1) * 32;
#pragma unroll
      for (int c = 0; c < 4; ++c)
        brg[nxt][c] = *(const u32x4*)(bsrc + k0 + c * 8);
#pragma unroll
      for (int h = 0; h < 2; ++h) {
        a0[nxt][h] = *(const float4*)(as0 + k0 + h * 4);
        a1[nxt][h] = *(const float4*)(as1 + k0 + h * 4);
      }
    }
    // convert current A -> bf16 frags + seqb store (barrier-free path)
    u16x8 q0, q1;
#pragma unroll
    for (int h = 0; h < 2; ++h)
#pragma unroll
      for (int e = 0; e < 4; ++e) {
        q0[h * 4 + e] = bf16_rne(a0[cur][h][e]);
        q1[h * 4 + e] = bf16_rne(a1[cur][h][e]);
      }
    *(u16x8*)(sq0 + kt * 32) = q0;
    *(u16x8*)(sq1 + kt * 32) = q1;
    bf16x8 ah0 = *(bf16x8*)&q0;
    bf16x8 ah1 = *(bf16x8*)&q1;
#pragma unroll
    for (int fn = 0; fn < 16; ++fn) {
      bf16x8 bf = *(bf16x8*)&sB[cur][lg][(fn * 16 + l15) * 8];
      acc[0][fn] =
          __builtin_amdgcn_mfma_f32_16x16x32_bf16(ah0, bf, acc[0][fn], 0, 0, 0);
      acc[1][fn] =
          __builtin_amdgcn_mfma_f32_16x16x32_bf16(ah1, bf, acc[1][fn], 0, 0, 0);
    }
    if (kt < 7) {
#pragma unroll
      for (int c = 0; c < 4; ++c) *(u32x4*)&sB[nxt][c][t * 8] = brg[nxt][c];
      __syncthreads();  // one barrier per K-step
    }
  }

  // ---- fused step-0: e = exp(v . tanh(acc + hw0)) ----
  const int npb = N >> 7;  // blocks per batch
  const int b = (int)blockIdx.x / npb;
  const long n0 = rowbase - (long)b * N;
  float vf[16], hwf[16];
#pragma unroll
  for (int fn = 0; fn < 16; ++fn) {
    const int cc = fn * 16 + l15;
    vf[fn] = vatt[cc];
    hwf[fn] = hw0[b * 256 + cc];
  }
  float esl = 0.f;
#pragma unroll
  for (int fm = 0; fm < 2; ++fm)
#pragma unroll
    for (int r = 0; r < 4; ++r) {
      float s = 0.f;
#pragma unroll
      for (int fn = 0; fn < 16; ++fn)
        s = fmaf(vf[fn], fast_tanh(acc[fm][fn][r] + hwf[fn]), s);
#pragma unroll
      for (int off = 1; off < 16; off <<= 1) s += __shfl_xor(s, off, 16);
      if (l15 == 0) {
        const long n = n0 + w * 32 + fm * 16 + lg * 4 + r;
        float e = (mask[(long)b * N + n] > 0.f) ? __expf(s) : 0.f;
        wbuf[(long)b * N + n] = e;
        esl += e;
      }
    }
#pragma unroll
  for (int off = 1; off < 64; off <<= 1) esl += __shfl_xor(esl, off, 64);
  if (lane == 0) sredE[w] = esl;
  __syncthreads();
  if (t == 0)
    esum0[b * npb + (int)blockIdx.x % npb] =
        (sredE[0] + sredE[1]) + (sredE[2] + sredE[3]);

  // ---- SP store (bf16) ----
#pragma unroll
  for (int fm = 0; fm < 2; ++fm)
#pragma unroll
    for (int fn = 0; fn < 16; ++fn)
#pragma unroll
      for (int r = 0; r < 4; ++r) {
        const long grow = rowbase + w * 32 + fm * 16 + lg * 4 + r;
        SP[grow * 256 + fn * 16 + l15] = bf16_rne(acc[fm][fn][r]);
      }
}

// ---------------------------------------------------------------------------
// K1 (steps >= 1): scores + exp + block esum + vec partials, fused.
// ---------------------------------------------------------------------------
__global__ __launch_bounds__(256) void step_scores_vec(
    const u16* __restrict__ SP, const u16* __restrict__ seqb,
    const float* __restrict__ hw, const float* __restrict__ v,
    const float* __restrict__ mask, float* __restrict__ wbuf,
    float* __restrict__ esum1, float* __restrict__ part, int N, int B) {
  const int b = blockIdx.y, c = blockIdx.x, t = threadIdx.x;
  __shared__ float shw[256], sv_[256], se[256];
  shw[t] = hw[b * 256 + t];
  sv_[t] = v[t];
  __syncthreads();
  const long row = (long)b * N + c * 256 + t;
  const bf16x8* rp = (const bf16x8*)(SP + row * 256);
  float s = 0.f;
#pragma unroll 8
  for (int j = 0; j < 32; ++j) {
    bf16x8 q = rp[j];
#pragma unroll
    for (int e = 0; e < 8; ++e)
      s = fmaf(sv_[j * 8 + e], fast_tanh(bf16f((u16)q[e]) + shw[j * 8 + e]), s);
  }
  float ev = (mask[row] > 0.f) ? __expf(s) : 0.f;
  se[t] = ev;
  wbuf[row] = ev;
  __syncthreads();
  if (t < 64) {
    float s4 = (se[t] + se[t + 64]) + (se[t + 128] + se[t + 192]);
#pragma unroll
    for (int off = 1; off < 64; off <<= 1) s4 += __shfl_xor(s4, off, 64);
    if (t == 0) esum1[b * gridDim.x + c] = s4;
  }
  // phase 2: vec partials from seqb
  const int d4 = t & 63, isub = t >> 6;
  const u16* base = seqb + ((long)b * N + c * 256 + isub * 64) * 256 + d4 * 4;
  float a0 = 0, a1 = 0, a2 = 0, a3 = 0;
#pragma unroll 4
  for (int ii = 0; ii < 64; ++ii) {
    u16x4 q = *(const u16x4*)(base + (long)ii * 256);
    float wv = se[isub * 64 + ii];
    a0 = fmaf(wv, bf16f(q[0]), a0);
    a1 = fmaf(wv, bf16f(q[1]), a1);
    a2 = fmaf(wv, bf16f(q[2]), a2);
    a3 = fmaf(wv, bf16f(q[3]), a3);
  }
  float4 res = {a0, a1, a2, a3};
  *(float4*)&part[((long)(c * 4 + isub) * B + b) * 256 + d4 * 4] = res;
}

// ---------------------------------------------------------------------------
// step-0 vec partials only (e already in wbuf from GEMM epilogue)
// ---------------------------------------------------------------------------
__global__ __launch_bounds__(256) void vec_partial(
    const u16* __restrict__ seqb, const float* __restrict__ wbuf,
    float* __restrict__ part, int N, int B) {
  const int b = blockIdx.y, c = blockIdx.x, t = threadIdx.x;
  const int d4 = t & 63, isub = t >> 6;
  __shared__ float sw[256];
  sw[t] = wbuf[(long)b * N + c * 256 + t];
  __syncthreads();
  const u16* base = seqb + ((long)b * N + c * 256 + isub * 64) * 256 + d4 * 4;
  float a0 = 0, a1 = 0, a2 = 0, a3 = 0;
#pragma unroll 4
  for (int ii = 0; ii < 64; ++ii) {
    u16x4 q = *(const u16x4*)(base + (long)ii * 256);
    float wv = sw[isub * 64 + ii];
    a0 = fmaf(wv, bf16f(q[0]), a0);
    a1 = fmaf(wv, bf16f(q[1]), a1);
    a2 = fmaf(wv, bf16f(q[2]), a2);
    a3 = fmaf(wv, bf16f(q[3]), a3);
  }
  float4 res = {a0, a1, a2, a3};
  *(float4*)&part[((long)(c * 4 + isub) * B + b) * 256 + d4 * 4] = res;
}

// ---------------------------------------------------------------------------
// finalize: S-reduce, vec, GRU (j-split over blockIdx.x), w-normalize+out.
// grid (4, B)
// ---------------------------------------------------------------------------
__global__ __launch_bounds__(256) void finalize_gru(
    const float* __restrict__ part, const float* __restrict__ esumP, int ecnt,
    const float* __restrict__ hprev, const float* __restrict__ WT,
    const float* __restrict__ UT, const float* __restrict__ bih,
    const float* __restrict__ bhh, const float* __restrict__ wbuf,
    float* __restrict__ out, float* __restrict__ hnew, int N, int T, int step,
    int NP, int B) {
  const int q = blockIdx.x, b = blockIdx.y, t = threadIdx.x;
  __shared__ float sv[256], sh[256], sP[6][4][64];
  float S = 0.f;
  for (int i = 0; i < ecnt; ++i) S += esumP[b * ecnt + i];
  const float inv = 1.f / S;
  float a = 0.f;
  for (int cc = 0; cc < NP; ++cc) a += part[((long)cc * B + b) * 256 + t];
  sv[t] = a * inv;
  sh[t] = hprev[b * 256 + t];
  __syncthreads();
  const int j4 = t & 63, dg = t >> 6;
  const int j = q * 64 + j4;
  float g0 = 0, g1 = 0, g2 = 0, g3 = 0, g4 = 0, g5 = 0;
#pragma unroll 4
  for (int d = dg * 64; d < dg * 64 + 64; ++d) {
    const float vd = sv[d], hd = sh[d];
    const float* wr_ = WT + (long)d * 768 + j;
    const float* ur_ = UT + (long)d * 768 + j;
    g0 = fmaf(vd, wr_[0], g0);
    g1 = fmaf(vd, wr_[256], g1);
    g2 = fmaf(vd, wr_[512], g2);
    g3 = fmaf(hd, ur_[0], g3);
    g4 = fmaf(hd, ur_[256], g4);
    g5 = fmaf(hd, ur_[512], g5);
  }
  sP[0][dg][j4] = g0;
  sP[1][dg][j4] = g1;
  sP[2][dg][j4] = g2;
  sP[3][dg][j4] = g3;
  sP[4][dg][j4] = g4;
  sP[5][dg][j4] = g5;
  __syncthreads();
  if (t < 64) {
    const int jj = q * 64 + t;
    float xr = bih[jj], xz = bih[256 + jj], xn = bih[512 + jj];
    float hr = bhh[jj], hz = bhh[256 + jj], hn = bhh[512 + jj];
#pragma unroll
    for (int dgg = 0; dgg < 4; ++dgg) {
      xr += sP[0][dgg][t];
      xz += sP[1][dgg][t];
      xn += sP[2][dgg][t];
      hr += sP[3][dgg][t];
      hz += sP[4][dgg][t];
      hn += sP[5][dgg][t];
    }
    float rr = sigmoidf_(xr + hr);
    float zz = sigmoidf_(xz + hz);
    float nn = fast_tanh(xn + rr * hn);
    hnew[b * 256 + jj] = (1.f - zz) * nn + zz * sh[jj];
  }
  // normalized weights -> output
  const long ob = ((long)b * T + step) * N;
  const int nq = N >> 2;
  for (int i = 0; i * 256 < nq; ++i) {
    const int n = q * nq + i * 256 + t;
    out[ob + n] = wbuf[(long)b * N + n] * inv;
  }
}

// ---------------------------------------------------------------------------
extern "C" void kernel_launch(void* const* d_in, const int* in_sizes, int n_in,
                              void* d_out, int out_size, void* d_ws,
                              size_t ws_size, hipStream_t stream) {
  (void)n_in;
  (void)ws_size;
  const float* seq = (const float*)d_in[0];
  const float* hidden = (const float*)d_in[1];
  const float* mask = (const float*)d_in[2];
  const float* Wseq = (const float*)d_in[4];
  const float* Wh = (const float*)d_in[5];
  const float* vatt = (const float*)d_in[6];
  const float* Wih = (const float*)d_in[7];
  const float* Whh = (const float*)d_in[8];
  const float* bih = (const float*)d_in[9];
  const float* bhh = (const float*)d_in[10];
  float* out = (float*)d_out;

  const int P = in_sizes[6];
  const int D = in_sizes[4] / P;
  const int H = in_sizes[5] / P;
  const int B = in_sizes[1] / H;
  const int N = in_sizes[2] / B;
  const int T = out_size / (B * N);
  const long M = (long)B * N;
  const int NC = N / 256;
  const int npb = N / 128;

  char* p = (char*)d_ws;
  auto alloc = [&](size_t bytes) {
    char* r = p;
    p += (bytes + 255) & ~(size_t)255;
    return r;
  };
  u16* SP = (u16*)alloc((size_t)M * P * 2);
  u16* seqb = (u16*)alloc((size_t)M * D * 2);
  u16* Wtb = (u16*)alloc((size_t)P * D * 2);
  float* WihT = (float*)alloc((size_t)D * 3 * H * 4);
  float* WhhT = (float*)alloc((size_t)H * 3 * H * 4);
  float* wbuf = (float*)alloc((size_t)B * N * 4);
  float* hwbuf = (float*)alloc((size_t)B * P * 4);
  float* hA = (float*)alloc((size_t)B * H * 4);
  float* hB = (float*)alloc((size_t)B * H * 4);
  float* part = (float*)alloc((size_t)NC * 4 * B * 256 * 4);
  float* esum0 = (float*)alloc((size_t)B * npb * 4);
  float* esum1 = (float*)alloc((size_t)B * NC * 4);
  float* hbuf[2] = {hA, hB};

  prep_wt<<<dim3(D), dim3(P), 0, stream>>>(Wseq, Wtb, P, D);
  prep_grut<<<dim3(3 * H), dim3(D), 0, stream>>>(Wih, Whh, WihT, WhhT, 3 * H,
                                                 D);
  hw_kernel<<<dim3(B), dim3(256), 0, stream>>>(hidden, Wh, hwbuf);
  gemm_fused<<<dim3((int)(M / 128)), dim3(256), 0, stream>>>(
      seq, Wtb, hwbuf, vatt, mask, SP, seqb, wbuf, esum0, N);

  for (int t = 0; t < T; ++t) {
    if (t > 0) {
      hw_kernel<<<dim3(B), dim3(256), 0, stream>>>(hbuf[(t - 1) & 1], Wh,
                                                   hwbuf);
      step_scores_vec<<<dim3(NC, B), dim3(256), 0, stream>>>(
          SP, seqb, hwbuf, vatt, mask, wbuf, esum1, part, N, B);
    } else {
      vec_partial<<<dim3(NC, B), dim3(256), 0, stream>>>(seqb, wbuf, part, N,
                                                         B);
    }
    finalize_gru<<<dim3(4, B), dim3(256), 0, stream>>>(
        part, t == 0 ? esum0 : esum1, t == 0 ? npb : NC,
        t == 0 ? hidden : hbuf[(t - 1) & 1], WihT, WhhT, bih, bhh, wbuf, out,
        hbuf[t & 1], N, T, t, NC * 4, B);
  }
}